// Round 6
// baseline (32.508 us; speedup 1.0000x reference)
//
#include <hip/hip_runtime.h>
#include <hip/hip_bf16.h>

#define C_IN  32
#define C_OUT 64
#define HH    64
#define WW    64
#define SLICE 265   // LDS dwords per ic: 4 rows * 66 (parity-split 2x33) + 1 pad
                    // 8*SLICE % 32 = 8 -> ic-groups at bank offsets {0,8,16,24}
                    // -> exactly 2-way LDS aliasing (free, m136)

typedef __attribute__((ext_vector_type(8))) short short8v;
typedef __attribute__((ext_vector_type(4))) float f32x4;

static __device__ __forceinline__ unsigned short f2bf(float f) {
    unsigned u = __builtin_bit_cast(unsigned, f);
    unsigned r = (u + 0x7FFFu + ((u >> 16) & 1u)) >> 16;   // RNE
    return (unsigned short)r;
}
static __device__ __forceinline__ float bf2f(unsigned short b) {
    unsigned u = ((unsigned)b) << 16;
    return __builtin_bit_cast(float, u);
}

// ---------------------------------------------------------------------------
// Weight-product + B-fragment pack (cold kernel).
// W~_k = Ew(k) * (w_k if (p+k) odd), Ew(k) = prod_{j>=k, (p+j) even} w_j
// Bpk[p][part(h=0,l=1)][k(9)][octile(4)][lane(64)][j(8)]  (bf16)
//   lane = (ic>>3)*16 + (oc&15), j = ic&7, octile = oc>>4
// ---------------------------------------------------------------------------
__global__ void wprod_pack(const float* __restrict__ w, unsigned short* __restrict__ Bpk) {
    int t = blockIdx.x * 256 + threadIdx.x;
    if (t >= 2 * C_IN * C_OUT) return;
    int oc = t & 63;
    int ic = (t >> 6) & 31;
    int p  = t >> 11;
    const float* wp = w + (oc * C_IN + ic) * 9;
    float W[9];
    float Ew = 1.f;
    #pragma unroll
    for (int k = 8; k >= 0; --k) {
        float wk = wp[k];
        if (((p + k) & 1) == 0) { Ew *= wk; W[k] = Ew; }
        else                    { W[k] = wk * Ew; }
    }
    int lane = ((ic >> 3) << 4) + (oc & 15);
    int j    = ic & 7;
    int oct  = oc >> 4;
    #pragma unroll
    for (int k = 0; k < 9; ++k) {
        unsigned short hi = f2bf(W[k]);
        unsigned short lo = f2bf(W[k] - bf2f(hi));
        size_t ih = ((((size_t)(p * 2 + 0) * 9 + k) * 4 + oct) * 64 + lane) * 8 + j;
        size_t il = ((((size_t)(p * 2 + 1) * 9 + k) * 4 + oct) * 64 + lane) * 8 + j;
        Bpk[ih] = hi;
        Bpk[il] = lo;
    }
}

// ---------------------------------------------------------------------------
// GEMM body (parity compile-time). xt[a][k] -> X~ (suffix products); per-k:
// pack bf16 hi/lo A-frag (native casts -> v_cvt_pk_bf16_f32), 4 octiles x
// 3-term MFMA. C = Xh*Wh + Xl*Wh + Xh*Wl.
// ---------------------------------------------------------------------------
template<int P>
__device__ __forceinline__ void aeg_gemm(
    float (&xt)[8][9], const short8v* __restrict__ Bq,
    float* __restrict__ out, int n, int i0, int grp, int l)
{
    // X~: suffix products of odd-step x's; even steps multiply own x.
    #pragma unroll
    for (int a = 0; a < 8; ++a) {
        float Ox = 1.f;
        #pragma unroll
        for (int k = 8; k >= 0; --k) {
            if (((P + k) & 1) == 1) { Ox *= xt[a][k]; xt[a][k] = Ox; }
            else                    { xt[a][k] = xt[a][k] * Ox; }
        }
    }

    f32x4 acc[4];
    #pragma unroll
    for (int t = 0; t < 4; ++t) acc[t] = (f32x4){0.f, 0.f, 0.f, 0.f};

    const int base_h = (P * 2 + 0) * 9;
    const int base_l = (P * 2 + 1) * 9;

    #pragma unroll
    for (int k = 0; k < 9; ++k) {
        short8v ah, al;
        #pragma unroll
        for (int a = 0; a < 8; ++a) {
            float v  = xt[a][k];
            __hip_bfloat16 bh = __float2bfloat16(v);
            float fh = __bfloat162float(bh);
            __hip_bfloat16 bl = __float2bfloat16(v - fh);
            ah[a] = (short)__builtin_bit_cast(unsigned short, bh);
            al[a] = (short)__builtin_bit_cast(unsigned short, bl);
        }
        #pragma unroll
        for (int t = 0; t < 4; ++t) {
            short8v bh = Bq[((base_h + k) * 4 + t) * 64 + l];
            short8v bl = Bq[((base_l + k) * 4 + t) * 64 + l];
            acc[t] = __builtin_amdgcn_mfma_f32_16x16x32_bf16(ah, bh, acc[t], 0, 0, 0);
            acc[t] = __builtin_amdgcn_mfma_f32_16x16x32_bf16(al, bh, acc[t], 0, 0, 0);
            acc[t] = __builtin_amdgcn_mfma_f32_16x16x32_bf16(ah, bl, acc[t], 0, 0, 0);
        }
    }

    // Scatter C: row = (l>>4)*4 + r (position), col = l&15 (oc low).
    int colc = l & 15;
    int rgrp = l >> 4;
    #pragma unroll
    for (int t = 0; t < 4; ++t) {
        int oc = t * 16 + colc;
        #pragma unroll
        for (int r = 0; r < 4; ++r) {
            int q = grp * 16 + rgrp * 4 + r;
            int i = i0 + (q >> 5);
            int j = 2 * (q & 31) + ((i + P) & 1);
            out[(((size_t)n * C_OUT + oc) * HH + i) * WW + j] = acc[t][r];
        }
    }
}

// ---------------------------------------------------------------------------
// Main kernel: block = 1 n x 2 rows x 64 cols, 512 threads = 8 waves, 1
// block/CU. Wave w: parity p = w&1, M-group grp = w>>1. x-slab (32ic x 4rows
// x 66cols, halo zeroed) staged coalesced into parity-split LDS; each lane
// reads its 72 taps from LDS (2-way bank aliasing = free), builds A-frags in
// registers.
// ---------------------------------------------------------------------------
__global__ __launch_bounds__(512) void aeg_mfma(
    const float* __restrict__ x, const unsigned short* __restrict__ Bpk,
    float* __restrict__ out)
{
    __shared__ float xs[C_IN * SLICE];

    int bid = blockIdx.x;
    int br  = bid & 31;        // row-block (0..31), 2 rows each
    int n   = bid >> 5;        // batch (0..7)
    int i0  = br * 2;
    int tid = threadIdx.x;

    // Stage x slab: ic 0..31, rows i0-1..i0+2, cols -1..64 (66 staged cols).
    // LDS index: ic*SLICE + row*66 + (jj&1)*33 + ((jj+1)>>1), jj = s-1.
    for (int ll = tid; ll < C_IN * 4 * 66; ll += 512) {
        int ic  = ll / 264;
        int rem = ll - ic * 264;
        int row = rem / 66;
        int s   = rem - row * 66;
        int ii  = i0 - 1 + row;
        int jj  = s - 1;
        float v = 0.f;
        if ((unsigned)ii < 64u && (unsigned)jj < 64u)
            v = x[(((size_t)n * C_IN + ic) * HH + ii) * WW + jj];
        xs[ic * SLICE + row * 66 + ((s + 1) & 1) * 33 + (s >> 1)] = v;
    }
    __syncthreads();

    int w   = __builtin_amdgcn_readfirstlane(tid >> 6);  // wave 0..7
    int p   = w & 1;
    int grp = w >> 1;          // 0..3
    int l   = tid & 63;

    int qA = grp * 16 + (l & 15);
    int rb = qA >> 5;                      // wave-uniform: 0 or 1
    int iA = i0 + rb;
    int pj = (iA + p) & 1;                 // wave-uniform output-col parity
    int jA = 2 * (qA & 31) + pj;
    int hs = jA >> 1;
    int icb = (l >> 4) * 8;

    // Tap gather from LDS: sides (q=1-pj, h=hs,hs+1 -> ds_read2), center.
    float xt[8][9];
    const float* ps = xs + icb * SLICE + rb * 66 + (1 - pj) * 33 + hs;
    const float* pc = xs + icb * SLICE + rb * 66 + pj * 33 + hs + pj;
    #pragma unroll
    for (int a = 0; a < 8; ++a) {
        #pragma unroll
        for (int di = 0; di < 3; ++di) {
            xt[a][di * 3 + 0] = ps[a * SLICE + di * 66 + 0];
            xt[a][di * 3 + 2] = ps[a * SLICE + di * 66 + 1];
            xt[a][di * 3 + 1] = pc[a * SLICE + di * 66];
        }
    }

    const short8v* Bq = (const short8v*)Bpk;
    if (p == 0) aeg_gemm<0>(xt, Bq, out, n, i0, grp, l);
    else        aeg_gemm<1>(xt, Bq, out, n, i0, grp, l);
}

extern "C" void kernel_launch(void* const* d_in, const int* in_sizes, int n_in,
                              void* d_out, int out_size, void* d_ws, size_t ws_size,
                              hipStream_t stream) {
    const float* x = (const float*)d_in[0];
    const float* w = (const float*)d_in[1];
    float* out = (float*)d_out;
    unsigned short* Bpk = (unsigned short*)d_ws;   // 147,456 bytes

    wprod_pack<<<16, 256, 0, stream>>>(w, Bpk);
    aeg_mfma<<<256, 512, 0, stream>>>(x, Bpk, out);
}

// Round 7
// 26.909 us; speedup vs baseline: 1.2081x; 1.2081x over previous
//
#include <hip/hip_runtime.h>

#define C_IN  32
#define C_OUT 64
#define HH    64
#define WW    64

typedef __attribute__((ext_vector_type(8))) short short8v;
typedef __attribute__((ext_vector_type(4))) float f32x4;

static __device__ __forceinline__ unsigned short f2bf(float f) {
    unsigned u = __builtin_bit_cast(unsigned, f);
    unsigned r = (u + 0x7FFFu + ((u >> 16) & 1u)) >> 16;   // RNE
    return (unsigned short)r;
}
static __device__ __forceinline__ float bf2f(unsigned short b) {
    unsigned u = ((unsigned)b) << 16;
    return __builtin_bit_cast(float, u);
}

// ---------------------------------------------------------------------------
// Weight-product + B-fragment pack (cold kernel).
// W~_k = Ew(k) * (w_k if (p+k) odd), Ew(k) = prod_{j>=k, (p+j) even} w_j
// Bpk[p][part(h=0,l=1)][k(9)][octile(4)][lane(64)][j(8)]  (bf16)
//   lane = (ic>>3)*16 + (oc&15), j = ic&7, octile = oc>>4
// ---------------------------------------------------------------------------
__global__ void wprod_pack(const float* __restrict__ w, unsigned short* __restrict__ Bpk) {
    int t = blockIdx.x * 256 + threadIdx.x;
    if (t >= 2 * C_IN * C_OUT) return;
    int oc = t & 63;
    int ic = (t >> 6) & 31;
    int p  = t >> 11;
    const float* wp = w + (oc * C_IN + ic) * 9;
    float W[9];
    float Ew = 1.f;
    #pragma unroll
    for (int k = 8; k >= 0; --k) {
        float wk = wp[k];
        if (((p + k) & 1) == 0) { Ew *= wk; W[k] = Ew; }
        else                    { W[k] = wk * Ew; }
    }
    int lane = ((ic >> 3) << 4) + (oc & 15);
    int j    = ic & 7;
    int oct  = oc >> 4;
    #pragma unroll
    for (int k = 0; k < 9; ++k) {
        unsigned short hi = f2bf(W[k]);
        unsigned short lo = f2bf(W[k] - bf2f(hi));
        size_t ih = ((((size_t)(p * 2 + 0) * 9 + k) * 4 + oct) * 64 + lane) * 8 + j;
        size_t il = ((((size_t)(p * 2 + 1) * 9 + k) * 4 + oct) * 64 + lane) * 8 + j;
        Bpk[ih] = hi;
        Bpk[il] = lo;
    }
}

// ---------------------------------------------------------------------------
// GEMM body (parity compile-time). xt[a][k] holds this lane's taps for
// ic = icb+a; transformed in place to X~. 3-term split GEMM:
// C = Xh*Wh + Xl*Wh + Xh*Wl  (Xl*Wl ~ 2^-18, dropped).
// ---------------------------------------------------------------------------
template<int P>
__device__ __forceinline__ void aeg_gemm(
    float (&xt)[8][9], const short8v* __restrict__ Bq,
    float* __restrict__ out, int n, int i0, int grp, int l)
{
    // X~: suffix products of odd-step x's; even steps multiply own x.
    #pragma unroll
    for (int a = 0; a < 8; ++a) {
        float Ox = 1.f;
        #pragma unroll
        for (int k = 8; k >= 0; --k) {
            if (((P + k) & 1) == 1) { Ox *= xt[a][k]; xt[a][k] = Ox; }
            else                    { xt[a][k] = xt[a][k] * Ox; }
        }
    }

    f32x4 acc[4];
    #pragma unroll
    for (int t = 0; t < 4; ++t) acc[t] = (f32x4){0.f, 0.f, 0.f, 0.f};

    const int base_h = (P * 2 + 0) * 9;
    const int base_l = (P * 2 + 1) * 9;

    #pragma unroll
    for (int k = 0; k < 9; ++k) {
        short8v ah, al;
        #pragma unroll
        for (int a = 0; a < 8; ++a) {
            float v = xt[a][k];
            unsigned short h = f2bf(v);
            ah[a] = (short)h;
            al[a] = (short)f2bf(v - bf2f(h));
        }
        #pragma unroll
        for (int t = 0; t < 4; ++t) {
            short8v bh = Bq[((base_h + k) * 4 + t) * 64 + l];
            short8v bl = Bq[((base_l + k) * 4 + t) * 64 + l];
            acc[t] = __builtin_amdgcn_mfma_f32_16x16x32_bf16(ah, bh, acc[t], 0, 0, 0);
            acc[t] = __builtin_amdgcn_mfma_f32_16x16x32_bf16(al, bh, acc[t], 0, 0, 0);
            acc[t] = __builtin_amdgcn_mfma_f32_16x16x32_bf16(ah, bl, acc[t], 0, 0, 0);
        }
    }

    // Scatter C: row = (l>>4)*4 + r (position), col = l&15 (oc low).
    int colc = l & 15;
    int rgrp = l >> 4;
    #pragma unroll
    for (int t = 0; t < 4; ++t) {
        int oc = t * 16 + colc;
        #pragma unroll
        for (int r = 0; r < 4; ++r) {
            int q = grp * 16 + rgrp * 4 + r;
            int i = i0 + (q >> 5);
            int j = 2 * (q & 31) + ((i + P) & 1);
            out[(((size_t)n * C_OUT + oc) * HH + i) * WW + j] = acc[t][r];
        }
    }
}

// ---------------------------------------------------------------------------
// Main kernel: block = 1 n x 2 rows x 64 cols, 512 threads = 8 waves.
// Wave w: parity p = w&1, M-group grp = w>>1 (16 positions of that parity).
// Lane l: A-row = grp*16 + (l&15) -> (i,j); K-elems = ic (l>>4)*8 + j.
// A-frags built in registers from 72 global taps (no LDS).
// __launch_bounds__(512, 2): occupancy is structurally capped at 2 waves/EU
// (grid 256 x 8 waves on 256 CUs), so give the allocator the full 256-VGPR
// budget for in-flight load ILP instead of the default occupancy target.
// ---------------------------------------------------------------------------
__global__ __launch_bounds__(512, 2) void aeg_mfma(
    const float* __restrict__ x, const unsigned short* __restrict__ Bpk,
    float* __restrict__ out)
{
    int bid = blockIdx.x;
    int br  = bid & 31;        // row-block (0..31), 2 rows each
    int n   = bid >> 5;        // batch (0..7)
    int i0  = br * 2;
    int tid = threadIdx.x;
    int w   = __builtin_amdgcn_readfirstlane(tid >> 6);  // wave 0..7
    int p   = w & 1;
    int grp = w >> 1;          // 0..3
    int l   = tid & 63;

    int qA = grp * 16 + (l & 15);
    int iA = i0 + (qA >> 5);
    int jA = 2 * (qA & 31) + ((iA + p) & 1);
    int icb = (l >> 4) * 8;

    float xt[8][9];
    #pragma unroll
    for (int a = 0; a < 8; ++a) {
        const float* xb = x + ((size_t)n * C_IN + icb + a) * (HH * WW);
        #pragma unroll
        for (int di = 0; di < 3; ++di) {
            int ii = iA + di - 1;
            #pragma unroll
            for (int dj = 0; dj < 3; ++dj) {
                int jj = jA + dj - 1;
                bool ok = ((unsigned)ii < 64u) && ((unsigned)jj < 64u);
                xt[a][di * 3 + dj] = ok ? xb[ii * WW + jj] : 0.f;
            }
        }
    }

    const short8v* Bq = (const short8v*)Bpk;
    if (p == 0) aeg_gemm<0>(xt, Bq, out, n, i0, grp, l);
    else        aeg_gemm<1>(xt, Bq, out, n, i0, grp, l);
}

extern "C" void kernel_launch(void* const* d_in, const int* in_sizes, int n_in,
                              void* d_out, int out_size, void* d_ws, size_t ws_size,
                              hipStream_t stream) {
    const float* x = (const float*)d_in[0];
    const float* w = (const float*)d_in[1];
    float* out = (float*)d_out;
    unsigned short* Bpk = (unsigned short*)d_ws;   // 147,456 bytes

    wprod_pack<<<16, 256, 0, stream>>>(w, Bpk);
    aeg_mfma<<<256, 512, 0, stream>>>(x, Bpk, out);
}